// Round 11
// baseline (1439.215 us; speedup 1.0000x reference)
//
#include <hip/hip_runtime.h>
#include <hip/hip_fp16.h>
#include <math.h>

#define NN 50000
#define EE 800000
#define HIDDEN 128
#define NGRAPH 50

typedef _Float16 half8 __attribute__((ext_vector_type(8)));
typedef float f32x4 __attribute__((ext_vector_type(4)));

// ---------------- CSR degree count + weight transpose (union grid) ----------------
__global__ void k_degprep(const int* __restrict__ eidx, int* __restrict__ cnt,
                          const float* __restrict__ Wq, const float* __restrict__ Wk,
                          const float* __restrict__ Wv, const float* __restrict__ Ws,
                          _Float16* __restrict__ wt) {
    int b = blockIdx.x;
    int t = threadIdx.x;
    if (b < 3125) {
        int e = b * 256 + t;
        if (e < EE) atomicAdd(&cnt[eidx[EE + e]], 1);
    } else {
        int idx = (b - 3125) * 256 + t;   // 12 * 16384 fp16 transposed weights
        if (idx < 12 * 16384) {
            int mat = idx >> 14;
            int l = mat >> 2, w = mat & 3;
            int nk = idx & 16383;
            int n = nk >> 7, k = nk & 127;
            const float* W = (w == 0 ? Wq : w == 1 ? Wk : w == 2 ? Wv : Ws) + (size_t)l * 16384;
            wt[idx] = (_Float16)W[k * 128 + n];
        }
    }
}

// scan + housekeeping: exclusive-scan deg->row_ptr (4 elems/thread), zero cnt,
// zero bn_acc3 / gsum / gcnt
__global__ void k_scan(int* __restrict__ cnt, int* __restrict__ row_ptr,
                       float* __restrict__ bn_acc3, float* __restrict__ gsum,
                       int* __restrict__ gcnt) {
    __shared__ int wsum[16];
    __shared__ int carry_s;
    int t = threadIdx.x;
    int lane = t & 63, w = t >> 6;
    if (t < 768) bn_acc3[t] = 0.f;
    if (t < 64) { gsum[t] = 0.f; gcnt[t] = 0; }
    if (t == 0) carry_s = 0;
    __syncthreads();
    for (int base = 0; base < NN; base += 4096) {
        int i0 = base + t * 4;
        int v[4];
#pragma unroll
        for (int j = 0; j < 4; j++) v[j] = (i0 + j < NN) ? cnt[i0 + j] : 0;
        int s4 = v[0] + v[1] + v[2] + v[3];
        int s = s4;
#pragma unroll
        for (int o = 1; o < 64; o <<= 1) {
            int u = __shfl_up(s, o);
            if (lane >= o) s += u;
        }
        if (lane == 63) wsum[w] = s;
        __syncthreads();
        if (w == 0) {
            int ws = (lane < 16) ? wsum[lane] : 0;
#pragma unroll
            for (int o = 1; o < 16; o <<= 1) {
                int u = __shfl_up(ws, o);
                if (lane >= o) ws += u;
            }
            if (lane < 16) wsum[lane] = ws;
        }
        __syncthreads();
        int wpre = (w == 0) ? 0 : wsum[w - 1];
        int run = carry_s + wpre + s - s4;
#pragma unroll
        for (int j = 0; j < 4; j++) {
            if (i0 + j < NN) { row_ptr[i0 + j] = run; cnt[i0 + j] = 0; run += v[j]; }
        }
        __syncthreads();
        if (t == 0) carry_s += wsum[15];
        __syncthreads();
    }
    if (t == 0) row_ptr[NN] = carry_s;
}

// scatter: build CSR-ordered src-index and edge-attr arrays
__global__ void k_scatter(const int* __restrict__ eidx, const float* __restrict__ eattr,
                          const int* __restrict__ row_ptr,
                          int* __restrict__ cur, int* __restrict__ esrc, float* __restrict__ eat2) {
    int e = blockIdx.x * blockDim.x + threadIdx.x;
    if (e < EE) {
        int d = eidx[EE + e];
        int s = eidx[e];
        int p = atomicAdd(&cur[d], 1);
        int pos = row_ptr[d] + p;
        esrc[pos] = s;
        float2 ea = *(const float2*)&eattr[2 * (size_t)e];
        *(float2*)&eat2[2 * (size_t)pos] = ea;
    }
}

// ---- fused 4-way GEMM via f16 MFMA: q,xr fp32 out; k,v packed OCP fp8 e4m3.
// When use_ab: BN affine+ELU applied to input X (stats from bn_acc) during staging.
__global__ __launch_bounds__(256) void k_gemm4(
    const float* __restrict__ X, const _Float16* __restrict__ wt,
    const float* __restrict__ bq, const float* __restrict__ bk,
    const float* __restrict__ bv, const float* __restrict__ bs,
    const float* __restrict__ bn_acc, const float* __restrict__ gamma,
    const float* __restrict__ beta, int use_ab,
    float* __restrict__ qo, unsigned int* __restrict__ kvb, float* __restrict__ xro)
{
    __shared__ _Float16 xs[64][136];
    __shared__ float ab_s[256];
    int t = threadIdx.x;
    int m0 = blockIdx.x * 64;
    if (use_ab) {
        if (t < 128) {
            float mu = bn_acc[t] * (1.f / NN);
            float var = bn_acc[128 + t] * (1.f / NN) - mu * mu;
            float inv = rsqrtf(var + 1e-5f);
            float a = inv * gamma[t];
            ab_s[t] = a;
            ab_s[128 + t] = beta[t] - mu * a;
        }
        __syncthreads();
    }
#pragma unroll
    for (int i = 0; i < 8; ++i) {
        int f = t + 256 * i;          // float4 index within 64x32
        int r = f >> 5, c4 = (f & 31) << 2;
        float4 val = make_float4(0.f, 0.f, 0.f, 0.f);
        if (m0 + r < NN) val = *(const float4*)&X[(size_t)(m0 + r) * 128 + c4];
        if (use_ab) {
            float4 a = *(const float4*)&ab_s[c4];
            float4 bb = *(const float4*)&ab_s[128 + c4];
            float z;
            z = fmaf(val.x, a.x, bb.x); val.x = z > 0.f ? z : expm1f(z);
            z = fmaf(val.y, a.y, bb.y); val.y = z > 0.f ? z : expm1f(z);
            z = fmaf(val.z, a.z, bb.z); val.z = z > 0.f ? z : expm1f(z);
            z = fmaf(val.w, a.w, bb.w); val.w = z > 0.f ? z : expm1f(z);
        }
        _Float16* dst = &xs[r][c4];
        dst[0] = (_Float16)val.x; dst[1] = (_Float16)val.y;
        dst[2] = (_Float16)val.z; dst[3] = (_Float16)val.w;
    }
    __syncthreads();
    int lane = t & 63, wid = t >> 6;
    int quad = lane >> 4, l15 = lane & 15;
    int mrow = wid * 16;
    half8 afrag[4];
#pragma unroll
    for (int kk = 0; kk < 4; kk++)
        afrag[kk] = *(const half8*)&xs[mrow + l15][kk * 32 + quad * 8];

#pragma unroll
    for (int nt = 0; nt < 8; nt++) {
        int c = nt * 16 + l15;
        f32x4 acc[4];
#pragma unroll
        for (int w = 0; w < 4; w++) acc[w] = (f32x4){0.f, 0.f, 0.f, 0.f};
#pragma unroll
        for (int kk = 0; kk < 4; kk++) {
            half8 bf[4];
#pragma unroll
            for (int w = 0; w < 4; w++)
                bf[w] = *(const half8*)&wt[(size_t)w * 16384 + c * 128 + kk * 32 + quad * 8];
#pragma unroll
            for (int w = 0; w < 4; w++)
                acc[w] = __builtin_amdgcn_mfma_f32_16x16x32_f16(afrag[kk], bf[w], acc[w], 0, 0, 0);
        }
        float bqv = bq[c], bkv = bk[c], bvv = bv[c], bsv = bs[c];
        int nodebase = m0 + mrow + quad * 4;
#pragma unroll
        for (int r = 0; r < 4; r++) {
            int node = nodebase + r;
            bool ok = node < NN;
            float qv = acc[0][r] + bqv;
            float xv = acc[3][r] + bsv;
            float kf = acc[1][r] + bkv;
            float vf = acc[2][r] + bvv;
            float kf1 = __shfl_xor(kf, 1);
            float vf1 = __shfl_xor(vf, 1);
            if (ok) {
                qo[(size_t)node * 128 + c] = qv;
                xro[(size_t)node * 128 + c] = xv;
                if (!(lane & 1)) {
                    // pack {k[c],k[c+1],v[c],v[c+1]} as 4x fp8 e4m3 in one word
                    int w2 = __builtin_amdgcn_cvt_pk_fp8_f32(kf, kf1, 0, false);
                    w2 = __builtin_amdgcn_cvt_pk_fp8_f32(vf, vf1, w2, true);
                    kvb[(size_t)node * 64 + (c >> 1)] = (unsigned int)w2;
                }
            }
        }
    }
}

// ---------------- attention + gate + BN-stats: HALF-WAVE per node ----------------
// Lanes 0-31 process node A, lanes 32-63 node B: 4 channels/lane, 8-lane head
// reduce, kv gather uint2/lane. Each 8-slot group = 16 edges / 64 lines in flight.
__global__ __launch_bounds__(256) void k_attn(
    const float* __restrict__ q, const unsigned int* __restrict__ kvb,
    const float* __restrict__ xr,
    const int* __restrict__ esrc, const float* __restrict__ eat2,
    const int* __restrict__ row_ptr,
    const float* __restrict__ We, const float* __restrict__ be,
    const float* __restrict__ Wb,
    float* __restrict__ out2, float* __restrict__ bn_accum)
{
    int t = threadIdx.x;
    int lane = t & 63;
    int wid = t >> 6;
    int h = lane >> 5;          // half index: 0 = node A, 1 = node B
    int l32 = lane & 31;
    int c0 = l32 * 4;           // 4 channels per lane
    int hb = h * 32;            // shfl base for own half
    int gpair = blockIdx.x * 4 + wid;
    int npairs = gridDim.x * 4;
    const uint2* kv2 = (const uint2*)kvb;   // node row = 32 uint2
    float4 we0 = *(const float4*)&We[c0];
    float4 we1 = *(const float4*)&We[128 + c0];
    float4 beL = *(const float4*)&be[c0];
    float4 wb_o = *(const float4*)&Wb[c0];
    float4 wb_r = *(const float4*)&Wb[128 + c0];
    float4 wb_d = *(const float4*)&Wb[256 + c0];
    const float scale = 0.17677669529663687f;   // 1/sqrt(32)
    float bns[4] = {0.f, 0.f, 0.f, 0.f};
    float bnq[4] = {0.f, 0.f, 0.f, 0.f};

    for (int pr = gpair; pr < NN / 2; pr += npairs) {
        int n = 2 * pr + h;
        int rs = row_ptr[n];
        int re = row_ptr[n + 1];
        int deg = re - rs;
        int dA = __shfl(deg, 0);
        int dB = __shfl(deg, 32);
        int maxd = dA > dB ? dA : dB;
        float4 qv = *(const float4*)&q[(size_t)n * 128 + c0];
        float den = 0.f;
        float a0 = 0.f, a1 = 0.f, a2 = 0.f, a3 = 0.f;

        for (int cb = 0; cb < maxd; cb += 32) {
            int sv = 0;
            float2 av = make_float2(0.f, 0.f);
            if (cb + l32 < deg) {
                int mi = rs + cb + l32;
                sv = esrc[mi];
                av = *(const float2*)&eat2[2 * (size_t)mi];
            }
            int cmax = maxd - cb; if (cmax > 32) cmax = 32;
            int m = deg - cb;               // per-half valid count (may be <=0)
            for (int base = 0; base < cmax; base += 8) {
                int s[8];
#pragma unroll
                for (int j = 0; j < 8; j++) s[j] = __shfl(sv, hb + base + j);
                uint2 kk[8];
#pragma unroll
                for (int j = 0; j < 8; j++)
                    kk[j] = kv2[(size_t)s[j] * 32 + l32];
#pragma unroll
                for (int j = 0; j < 8; j++) {
                    float eax = __shfl(av.x, hb + base + j);
                    float eay = __shfl(av.y, hb + base + j);
                    auto k01 = __builtin_amdgcn_cvt_pk_f32_fp8((int)kk[j].x, false);
                    auto v01 = __builtin_amdgcn_cvt_pk_f32_fp8((int)kk[j].x, true);
                    auto k23 = __builtin_amdgcn_cvt_pk_f32_fp8((int)kk[j].y, false);
                    auto v23 = __builtin_amdgcn_cvt_pk_f32_fp8((int)kk[j].y, true);
                    float e0 = fmaf(eax, we0.x, fmaf(eay, we1.x, beL.x));
                    float e1 = fmaf(eax, we0.y, fmaf(eay, we1.y, beL.y));
                    float e2 = fmaf(eax, we0.z, fmaf(eay, we1.z, beL.z));
                    float e3 = fmaf(eax, we0.w, fmaf(eay, we1.w, beL.w));
                    float p = qv.x * (k01[0] + e0) + qv.y * (k01[1] + e1)
                            + qv.z * (k23[0] + e2) + qv.w * (k23[1] + e3);
                    p += __shfl_xor(p, 1);      // head = 8 lanes (32 ch / 4 per lane)
                    p += __shfl_xor(p, 2);
                    p += __shfl_xor(p, 4);
                    float alpha = (base + j < m) ? p * scale : -1.0e30f;
                    float exv = __expf(alpha);
                    den += exv;
                    a0 = fmaf(exv, v01[0] + e0, a0);
                    a1 = fmaf(exv, v01[1] + e1, a1);
                    a2 = fmaf(exv, v23[0] + e2, a2);
                    a3 = fmaf(exv, v23[1] + e3, a3);
                }
            }
        }
        float rden = 1.f / (den + 1e-16f);
        a0 *= rden; a1 *= rden; a2 *= rden; a3 *= rden;
        // beta gate (dot over 128 ch = 32 lanes of own half)
        float4 xv = *(const float4*)&xr[(size_t)n * 128 + c0];
        float gp = a0 * wb_o.x + a1 * wb_o.y + a2 * wb_o.z + a3 * wb_o.w
                 + xv.x * wb_r.x + xv.y * wb_r.y + xv.z * wb_r.z + xv.w * wb_r.w
                 + (a0 - xv.x) * wb_d.x + (a1 - xv.y) * wb_d.y
                 + (a2 - xv.z) * wb_d.z + (a3 - xv.w) * wb_d.w;
        gp += __shfl_xor(gp, 1);
        gp += __shfl_xor(gp, 2);
        gp += __shfl_xor(gp, 4);
        gp += __shfl_xor(gp, 8);
        gp += __shfl_xor(gp, 16);
        float gate = 1.f / (1.f + __expf(-gp));
        float o0 = gate * xv.x + (1.f - gate) * a0;
        float o1 = gate * xv.y + (1.f - gate) * a1;
        float o2 = gate * xv.z + (1.f - gate) * a2;
        float o3 = gate * xv.w + (1.f - gate) * a3;
        *(float4*)&out2[(size_t)n * 128 + c0] = make_float4(o0, o1, o2, o3);
        bns[0] += o0; bnq[0] = fmaf(o0, o0, bnq[0]);
        bns[1] += o1; bnq[1] = fmaf(o1, o1, bnq[1]);
        bns[2] += o2; bnq[2] = fmaf(o2, o2, bnq[2]);
        bns[3] += o3; bnq[3] = fmaf(o3, o3, bnq[3]);
    }
    // block-level BN partial reduce: lane covers channels 4*l32..+3 (t&31 = l32)
    __shared__ float s_sum[4][256], s_sq[4][256];
#pragma unroll
    for (int i = 0; i < 4; i++) { s_sum[i][t] = bns[i]; s_sq[i][t] = bnq[i]; }
    __syncthreads();
    if (t < 32) {
#pragma unroll
        for (int i = 0; i < 4; i++) {
            float sx = 0.f, qx = 0.f;
#pragma unroll
            for (int j = 0; j < 8; j++) {
                sx += s_sum[i][t + 32 * j];
                qx += s_sq[i][t + 32 * j];
            }
            atomicAdd(&bn_accum[4 * t + i], sx);
            atomicAdd(&bn_accum[128 + 4 * t + i], qx);
        }
    }
}

// ------- readout: BN affine+ELU+dot(Wout), LDS per-graph accumulate, one flush per block -------
__global__ __launch_bounds__(256) void k_pool(const float* __restrict__ x,
                                              const float* __restrict__ bn_acc,
                                              const float* __restrict__ gamma,
                                              const float* __restrict__ beta,
                                              const float* __restrict__ Wout,
                                              const int* __restrict__ batch,
                                              float* __restrict__ gsum, int* __restrict__ gcnt) {
    __shared__ float lsum[NGRAPH];
    __shared__ int lcnt[NGRAPH];
    __shared__ float ab_s[256];
    int t = threadIdx.x;
    if (t < NGRAPH) { lsum[t] = 0.f; lcnt[t] = 0; }
    if (t < 128) {
        float mu = bn_acc[t] * (1.f / NN);
        float var = bn_acc[128 + t] * (1.f / NN) - mu * mu;
        float inv = rsqrtf(var + 1e-5f);
        float a = inv * gamma[t];
        ab_s[t] = a;
        ab_s[128 + t] = beta[t] - mu * a;
    }
    __syncthreads();
    int lane = t & 63;
    int wid = t >> 6;
    int ch = lane * 2;
    float2 wo = *(const float2*)&Wout[ch];
    float2 a = *(const float2*)&ab_s[ch];
    float2 b = *(const float2*)&ab_s[128 + ch];
    int base = blockIdx.x * 16 + wid * 4;
#pragma unroll
    for (int i = 0; i < 4; i++) {
        int n = base + i;
        if (n < NN) {
            float2 xv = *(const float2*)&x[(size_t)n * 128 + ch];
            float z0 = fmaf(xv.x, a.x, b.x); z0 = z0 > 0.f ? z0 : expm1f(z0);
            float z1 = fmaf(xv.y, a.y, b.y); z1 = z1 > 0.f ? z1 : expm1f(z1);
            float p = z0 * wo.x + z1 * wo.y;
            p += __shfl_xor(p, 1);
            p += __shfl_xor(p, 2);
            p += __shfl_xor(p, 4);
            p += __shfl_xor(p, 8);
            p += __shfl_xor(p, 16);
            p += __shfl_xor(p, 32);
            if (lane == 0) {
                int g = batch[n];
                atomicAdd(&lsum[g], p);
                atomicAdd(&lcnt[g], 1);
            }
        }
    }
    __syncthreads();
    if (t < NGRAPH && lcnt[t] > 0) {
        atomicAdd(&gsum[t], lsum[t]);
        atomicAdd(&gcnt[t], lcnt[t]);
    }
}

__global__ void k_final(const float* __restrict__ gsum, const int* __restrict__ gcnt,
                        const float* __restrict__ bout, const float* __restrict__ obias,
                        float* __restrict__ out) {
    int g = threadIdx.x;
    if (g < NGRAPH) out[g] = gsum[g] / fmaxf((float)gcnt[g], 1.f) + bout[0] + obias[0];
}

extern "C" void kernel_launch(void* const* d_in, const int* in_sizes, int n_in,
                              void* d_out, int out_size, void* d_ws, size_t ws_size,
                              hipStream_t stream) {
    const float* x_in       = (const float*)d_in[0];
    const int* eidx         = (const int*)d_in[1];
    const float* eattr      = (const float*)d_in[2];
    const int* batch        = (const int*)d_in[3];
    const float* Wq         = (const float*)d_in[4];
    const float* bq         = (const float*)d_in[5];
    const float* Wk         = (const float*)d_in[6];
    const float* bk         = (const float*)d_in[7];
    const float* Wv         = (const float*)d_in[8];
    const float* bv         = (const float*)d_in[9];
    const float* We         = (const float*)d_in[10];
    const float* be         = (const float*)d_in[11];
    const float* Wskip      = (const float*)d_in[12];
    const float* bskip      = (const float*)d_in[13];
    const float* Wbeta      = (const float*)d_in[14];
    const float* bn_gamma   = (const float*)d_in[15];
    const float* bn_beta    = (const float*)d_in[16];
    const float* Wout       = (const float*)d_in[17];
    const float* bout       = (const float*)d_in[18];
    const float* obias      = (const float*)d_in[19];
    float* out = (float*)d_out;

    char* ws = (char*)d_ws;
    size_t off = 0;
    auto alloc = [&](size_t bytes) -> void* {
        off = (off + 255) & ~(size_t)255;
        void* p = ws + off;
        off += bytes;
        return p;
    };
    const size_t NF = (size_t)NN * 128 * sizeof(float);
    float* xbuf    = (float*)alloc(NF);
    float* qb      = (float*)alloc(NF);
    float* xrb     = (float*)alloc(NF);
    unsigned int* kvb = (unsigned int*)alloc((size_t)NN * 64 * sizeof(unsigned int));
    _Float16* wt   = (_Float16*)alloc((size_t)12 * 16384 * sizeof(_Float16));
    int* row_ptr   = (int*)alloc((NN + 1) * sizeof(int));
    int* cnt       = (int*)alloc(NN * sizeof(int));
    int* esrc      = (int*)alloc(EE * sizeof(int));
    float* eat2    = (float*)alloc((size_t)EE * 2 * sizeof(float));
    float* bn_acc3 = (float*)alloc(3 * 256 * sizeof(float));
    float* gsum    = (float*)alloc(64 * sizeof(float));
    int* gcnt      = (int*)alloc(64 * sizeof(int));
    (void)ws_size; (void)n_in; (void)in_sizes; (void)out_size;

    // ---- CSR build (dst -> src, eattr reordered) + zero aux buffers + weight prep ----
    hipMemsetAsync(cnt, 0, NN * sizeof(int), stream);
    k_degprep<<<3125 + 768, 256, 0, stream>>>(eidx, cnt, Wq, Wk, Wv, Wskip, wt);
    k_scan<<<1, 1024, 0, stream>>>(cnt, row_ptr, bn_acc3, gsum, gcnt);
    k_scatter<<<(EE + 255) / 256, 256, 0, stream>>>(eidx, eattr, row_ptr, cnt, esrc, eat2);

    // ---- layers ----
    for (int l = 0; l < 3; ++l) {
        const float* Xl = (l == 0) ? x_in : xbuf;
        const float* prev_acc = (l == 0) ? bn_acc3 : bn_acc3 + (l - 1) * 256;
        k_gemm4<<<(NN + 63) / 64, 256, 0, stream>>>(
            Xl, wt + (size_t)l * 65536,
            bq + l * 128, bk + l * 128, bv + l * 128, bskip + l * 128,
            prev_acc, bn_gamma + (l == 0 ? 0 : (l - 1) * 128),
            bn_beta + (l == 0 ? 0 : (l - 1) * 128), (l == 0) ? 0 : 1,
            qb, kvb, xrb);
        k_attn<<<3125, 256, 0, stream>>>(
            qb, kvb, xrb, esrc, eat2, row_ptr,
            We + (size_t)l * 256, be + l * 128, Wbeta + (size_t)l * 384,
            xbuf, bn_acc3 + l * 256);
    }

    // ---- readout (BN affine+ELU of layer-2 fused in) ----
    k_pool<<<(NN + 15) / 16, 256, 0, stream>>>(xbuf, bn_acc3 + 2 * 256,
                                               bn_gamma + 2 * 128, bn_beta + 2 * 128,
                                               Wout, batch, gsum, gcnt);
    k_final<<<1, 64, 0, stream>>>(gsum, gcnt, bout, obias, out);
}